// Round 5
// baseline (695.367 us; speedup 1.0000x reference)
//
#include <hip/hip_runtime.h>
#include <cstdint>

// ---------------------------------------------------------------------------
// CrossAttentionBlock: q/k/v proj (bf16 MFMA; K/V rows zeroed where masked) ->
// flash attention (32x32 MFMA, fixed-m softmax, wave+block KV split, pure-sum
// merges) -> merge -> o proj (+residual) -> LayerNorm.
// B=2, SQ=1024, SKV=4096, E=1024, H=16, D=64.
// Fixed-m softmax: p = 2^(s*log2e/8 - 10). Masked kv have K=V=0 => s==0
// exactly => p = 2^-10 exactly; contributes 0 to O and n_masked*2^-10 to l,
// subtracted at merge. Valid because scores are bounded (|arg| < 20 << 127).
// ---------------------------------------------------------------------------

typedef __bf16 bf16x8_t  __attribute__((ext_vector_type(8)));
typedef float  f32x4_t   __attribute__((ext_vector_type(4)));
typedef float  f32x16_t  __attribute__((ext_vector_type(16)));

#define E_DIM 1024
#define NH    16
#define HD    64
#define SCALE_L2E 0.1803368804f   // (1/8) * log2(e)
#define FIXM  10.0f

__device__ __forceinline__ unsigned short f32_bf16(float f) {
    union { float f; unsigned int u; } v; v.f = f;
    unsigned int u = v.u;
    unsigned int r = (u + 0x7fffu + ((u >> 16) & 1u)) >> 16;  // RNE
    return (unsigned short)r;
}

__device__ __forceinline__ unsigned pack_bf16(float a, float b) {
    __bf16 x = (__bf16)a, y = (__bf16)b;
    unsigned short ux = __builtin_bit_cast(unsigned short, x);
    unsigned short uy = __builtin_bit_cast(unsigned short, y);
    return (unsigned)ux | ((unsigned)uy << 16);
}

// async global->LDS, 16B per lane; lds base must be wave-uniform
__device__ __forceinline__ void gld16(const unsigned short* g, unsigned short* l) {
    __builtin_amdgcn_global_load_lds(
        (const __attribute__((address_space(1))) unsigned int*)g,
        (__attribute__((address_space(3))) unsigned int*)l, 16, 0, 0);
}

// ---------------- fused fp32 -> bf16 casts (all 6 tensors) -----------------
__global__ void cast_all(const float* __restrict__ q, const float* __restrict__ kv,
                         const float* __restrict__ wq, const float* __restrict__ wk,
                         const float* __restrict__ wv, const float* __restrict__ wo,
                         unsigned short* __restrict__ Xq, unsigned short* __restrict__ Xkv,
                         unsigned short* __restrict__ Wqb, unsigned short* __restrict__ Wkb,
                         unsigned short* __restrict__ Wvb, unsigned short* __restrict__ Wob) {
    long i = (long)blockIdx.x * 256 + threadIdx.x;   // float4 index
    const float* src; unsigned short* dst; long off;
    if (i < 2621440) {
        if (i < 524288) { src = q;  dst = Xq;  off = i; }
        else            { src = kv; dst = Xkv; off = i - 524288; }
    } else {
        long j = i - 2621440;
        int w = (int)(j >> 18); off = j & 262143;
        src = (w == 0) ? wq : (w == 1) ? wk : (w == 2) ? wv : wo;
        dst = (w == 0) ? Wqb : (w == 1) ? Wkb : (w == 2) ? Wvb : Wob;
    }
    float4 v = reinterpret_cast<const float4*>(src)[off];
    ushort4 o;
    o.x = f32_bf16(v.x); o.y = f32_bf16(v.y);
    o.z = f32_bf16(v.z); o.w = f32_bf16(v.w);
    reinterpret_cast<ushort4*>(dst)[off] = o;
}

// ---------------- count masked kv per batch -> n_masked * 2^-10 ------------
__global__ void count_mask(const int* __restrict__ m, float* __restrict__ Sub) {
    __shared__ int red[4];
    int b = blockIdx.x, t = threadIdx.x;
    int s = 0;
#pragma unroll
    for (int k = 0; k < 16; k++) s += (m[b * 4096 + k * 256 + t] != 0);
#pragma unroll
    for (int off = 32; off >= 1; off >>= 1) s += __shfl_xor(s, off, 64);
    if ((t & 63) == 0) red[t >> 6] = s;
    __syncthreads();
    if (t == 0)
        Sub[b] = (float)(4096 - (red[0] + red[1] + red[2] + red[3])) * 0.0009765625f;
}

// ---------------- GEMM: C = A @ W^T + bias (m97-style staging) -------------
// mode 0: [B,H,S,D] (Q, no mask).  mode 1: [B,H,S,D], masked rows zeroed (K).
// mode 2: [B,H,D,S] (V^T), masked cols zeroed.
#define BM 128
#define BN 128
#define BK 64

__global__ __launch_bounds__(256) void gemm_qkv(
    const unsigned short* __restrict__ A,
    const unsigned short* __restrict__ W,
    const float* __restrict__ bias,
    unsigned short* __restrict__ out,
    int lgS, int mode, const int* __restrict__ kvm)
{
    __shared__ __align__(16) unsigned short As[BM * BK];
    __shared__ __align__(16) unsigned short Bs[BN * BK];
    int tid  = threadIdx.x;
    int m0   = blockIdx.y * BM;
    int n0   = blockIdx.x * BN;
    int lane = tid & 63;
    int wvu  = __builtin_amdgcn_readfirstlane(tid >> 6);
    int l15  = lane & 15, quad = lane >> 4, x7 = l15 & 7;
    int wm   = ((tid >> 6) >> 1) * 64, wn = ((tid >> 6) & 1) * 64;

    f32x4_t acc[4][4];
#pragma unroll
    for (int i = 0; i < 4; i++)
#pragma unroll
        for (int j = 0; j < 4; j++) acc[i][j] = (f32x4_t)(0.f);

    for (int k0 = 0; k0 < 1024; k0 += BK) {
        __syncthreads();
#pragma unroll
        for (int i = 0; i < 4; i++) {
            int s = (i * 4 + wvu) * 64 + lane;
            int row = s >> 3, pcol = ((s & 7) ^ (row & 7)) << 3;
            gld16(&A[(long)(m0 + row) * 1024 + k0 + pcol], &As[(i * 4 + wvu) * 512]);
            gld16(&W[(long)(n0 + row) * 1024 + k0 + pcol], &Bs[(i * 4 + wvu) * 512]);
        }
        __syncthreads();
        const char* Ab = (const char*)As;
        const char* Bb = (const char*)Bs;
#pragma unroll
        for (int ks = 0; ks < 2; ks++) {
            int pos = (((ks << 2) + quad) ^ x7) << 4;
            bf16x8_t af[4], bf[4];
#pragma unroll
            for (int mi = 0; mi < 4; mi++)
                af[mi] = *reinterpret_cast<const bf16x8_t*>(
                    Ab + (wm + mi * 16 + l15) * 128 + pos);
#pragma unroll
            for (int ni = 0; ni < 4; ni++)
                bf[ni] = *reinterpret_cast<const bf16x8_t*>(
                    Bb + (wn + ni * 16 + l15) * 128 + pos);
#pragma unroll
            for (int mi = 0; mi < 4; mi++)
#pragma unroll
                for (int ni = 0; ni < 4; ni++)
                    acc[mi][ni] = __builtin_amdgcn_mfma_f32_16x16x32_bf16(
                        af[mi], bf[ni], acc[mi][ni], 0, 0, 0);
        }
    }
    int Smask = (1 << lgS) - 1;
    if (mode == 0) {
#pragma unroll
        for (int mi = 0; mi < 4; mi++)
#pragma unroll
            for (int ni = 0; ni < 4; ni++) {
                int n = n0 + wn + ni * 16 + l15;
                float bv = bias[n];
                int h = n >> 6, d = n & 63;
#pragma unroll
                for (int r = 0; r < 4; r++) {
                    int mg = m0 + wm + mi * 16 + quad * 4 + r;
                    int b = mg >> lgS, s = mg & Smask;
                    out[(((b * NH + h) << lgS) + s) * HD + d] =
                        f32_bf16(acc[mi][ni][r] + bv);
                }
            }
    } else if (mode == 1) {
#pragma unroll
        for (int mi = 0; mi < 4; mi++)
#pragma unroll
            for (int ni = 0; ni < 4; ni++) {
                int n = n0 + wn + ni * 16 + l15;
                float bv = bias[n];
                int h = n >> 6, d = n & 63;
#pragma unroll
                for (int r = 0; r < 4; r++) {
                    int mg = m0 + wm + mi * 16 + quad * 4 + r;
                    int b = mg >> lgS, s = mg & Smask;
                    unsigned short val = kvm[(b << lgS) + s]
                        ? f32_bf16(acc[mi][ni][r] + bv) : (unsigned short)0;
                    out[(((b * NH + h) << lgS) + s) * HD + d] = val;
                }
            }
    } else {
#pragma unroll
        for (int mi = 0; mi < 4; mi++)
#pragma unroll
            for (int ni = 0; ni < 4; ni++) {
                int n = n0 + wn + ni * 16 + l15;
                float bv = bias[n];
                int h = n >> 6, d = n & 63;
                int mg0 = m0 + wm + mi * 16 + quad * 4;
                int b = mg0 >> lgS, s = mg0 & Smask;
                int4 mk = *reinterpret_cast<const int4*>(&kvm[(b << lgS) + s]);
                ushort4 w;
                w.x = mk.x ? f32_bf16(acc[mi][ni][0] + bv) : (unsigned short)0;
                w.y = mk.y ? f32_bf16(acc[mi][ni][1] + bv) : (unsigned short)0;
                w.z = mk.z ? f32_bf16(acc[mi][ni][2] + bv) : (unsigned short)0;
                w.w = mk.w ? f32_bf16(acc[mi][ni][3] + bv) : (unsigned short)0;
                *reinterpret_cast<ushort4*>(
                    &out[(((b * NH + h) * HD + d) << lgS) + s]) = w;
            }
    }
}

// ---------------- O-proj GEMM + bias + residual -> fp32 --------------------
__global__ __launch_bounds__(256) void gemm_oproj(
    const unsigned short* __restrict__ A,
    const unsigned short* __restrict__ W,
    const float* __restrict__ bias,
    const float* __restrict__ resid,
    float* __restrict__ xout)
{
    __shared__ __align__(16) unsigned short As[BM * BK];
    __shared__ __align__(16) unsigned short Bs[BN * BK];
    int tid  = threadIdx.x;
    int m0   = blockIdx.y * BM;
    int n0   = blockIdx.x * BN;
    int lane = tid & 63;
    int wvu  = __builtin_amdgcn_readfirstlane(tid >> 6);
    int l15  = lane & 15, quad = lane >> 4, x7 = l15 & 7;
    int wm   = ((tid >> 6) >> 1) * 64, wn = ((tid >> 6) & 1) * 64;

    f32x4_t acc[4][4];
#pragma unroll
    for (int i = 0; i < 4; i++)
#pragma unroll
        for (int j = 0; j < 4; j++) acc[i][j] = (f32x4_t)(0.f);

    for (int k0 = 0; k0 < 1024; k0 += BK) {
        __syncthreads();
#pragma unroll
        for (int i = 0; i < 4; i++) {
            int s = (i * 4 + wvu) * 64 + lane;
            int row = s >> 3, pcol = ((s & 7) ^ (row & 7)) << 3;
            gld16(&A[(long)(m0 + row) * 1024 + k0 + pcol], &As[(i * 4 + wvu) * 512]);
            gld16(&W[(long)(n0 + row) * 1024 + k0 + pcol], &Bs[(i * 4 + wvu) * 512]);
        }
        __syncthreads();
        const char* Ab = (const char*)As;
        const char* Bb = (const char*)Bs;
#pragma unroll
        for (int ks = 0; ks < 2; ks++) {
            int pos = (((ks << 2) + quad) ^ x7) << 4;
            bf16x8_t af[4], bf[4];
#pragma unroll
            for (int mi = 0; mi < 4; mi++)
                af[mi] = *reinterpret_cast<const bf16x8_t*>(
                    Ab + (wm + mi * 16 + l15) * 128 + pos);
#pragma unroll
            for (int ni = 0; ni < 4; ni++)
                bf[ni] = *reinterpret_cast<const bf16x8_t*>(
                    Bb + (wn + ni * 16 + l15) * 128 + pos);
#pragma unroll
            for (int mi = 0; mi < 4; mi++)
#pragma unroll
                for (int ni = 0; ni < 4; ni++)
                    acc[mi][ni] = __builtin_amdgcn_mfma_f32_16x16x32_bf16(
                        af[mi], bf[ni], acc[mi][ni], 0, 0, 0);
        }
    }
#pragma unroll
    for (int mi = 0; mi < 4; mi++)
#pragma unroll
        for (int ni = 0; ni < 4; ni++) {
            int n = n0 + wn + ni * 16 + l15;
            float bv = bias[n];
#pragma unroll
            for (int r = 0; r < 4; r++) {
                int mg = m0 + wm + mi * 16 + quad * 4 + r;
                xout[mg * 1024 + n] = acc[mi][ni][r] + bv + resid[mg * 1024 + n];
            }
        }
}

// ---------------- flash attention (32x32 MFMA, fixed-m, kv-split) ----------
// grid 1024 blocks of 256.  Block = 64 q of one (b,h) x one kv half (2048).
// Waves own 32-kv strips of each 128 tile.  No online max: p=2^(s*c-10).
// Partials merge by pure addition (in-block via 32KB LDS, cross-block later).
__global__ __launch_bounds__(256, 4) void attn_kernel(
    const unsigned short* __restrict__ Q,   // [B,NH,1024,64]
    const unsigned short* __restrict__ K,   // [B,NH,4096,64]  masked rows = 0
    const unsigned short* __restrict__ VT,  // [B,NH,64,4096]  masked cols = 0
    float* __restrict__ Osc,                // [2][32][1024][64] fp32 partial O
    float* __restrict__ Lsc)                // [2][32][1024] partial l
{
    __shared__ __align__(16) union {
        struct { unsigned short Ks[128 * 64]; unsigned short Vt[64 * 128]; } st;
        float OL[2 * 4096];                 // two 16KB merge regions
    } sm;
    __shared__ float lsm[4][64];

    int tid  = threadIdx.x;
    int lane = tid & 63;
    int w    = tid >> 6;
    int wvu  = __builtin_amdgcn_readfirstlane(w);
    int l31  = lane & 31, hw = lane >> 5;

    // XCD-grouped: 4 (b,h) per XCD; q-tiles and halves of one bh share L2
    int bid  = blockIdx.x;
    int xcd  = bid & 7, gidx = bid >> 3;
    int bh   = xcd * 4 + (gidx & 3);
    int rest = gidx >> 2;                    // 0..31
    int q0   = (rest & 15) * 64;
    int half = rest >> 4;

    const unsigned short* Kb = K + ((long)bh * 4096 + half * 2048) * HD;
    const unsigned short* Vb = VT + (long)bh * HD * 4096 + half * 2048;
    const unsigned short* Qb = Q + ((long)bh * 1024 + q0) * HD;

    // Q fragments (B-operand): B[n=q=l31][k=hw*8+j], 2 q-subtiles x 4 k-chunks
    bf16x8_t qfr[2][4];
#pragma unroll
    for (int qi = 0; qi < 2; qi++)
#pragma unroll
        for (int ks = 0; ks < 4; ks++)
            qfr[qi][ks] = *reinterpret_cast<const bf16x8_t*>(
                Qb + (qi * 32 + l31) * HD + ks * 16 + hw * 8);

    f32x16_t oacc[2][2];
#pragma unroll
    for (int i = 0; i < 2; i++)
#pragma unroll
        for (int j = 0; j < 2; j++) oacc[i][j] = (f32x16_t)(0.f);
    float l_run[2] = { 0.f, 0.f };

    const char* Kc = (const char*)sm.st.Ks;
    const char* Vc = (const char*)sm.st.Vt;

    for (int kt = 0; kt < 16; kt++) {
        int kv0 = kt * 128;
        __syncthreads();
#pragma unroll
        for (int i = 0; i < 4; i++) {
            int s = (i * 4 + wvu) * 64 + lane;
            int row = s >> 3, pc = ((s & 7) ^ (row & 7)) << 3;
            gld16(&Kb[(long)(kv0 + row) * HD + pc], &sm.st.Ks[(i * 4 + wvu) * 512]);
            int rv = s >> 4, pv2 = ((s & 15) ^ (rv & 15)) << 3;
            gld16(&Vb[(long)rv * 4096 + kv0 + pv2], &sm.st.Vt[(i * 4 + wvu) * 512]);
        }
        __syncthreads();

        // ---- S^T: C[kv 32][q 32] per q-subtile; kv rows = w*32.. ----
        f32x16_t sa[2];
        sa[0] = (f32x16_t)(0.f); sa[1] = (f32x16_t)(0.f);
        int krow = w * 32 + l31;
#pragma unroll
        for (int ks = 0; ks < 4; ks++) {
            int phys = (ks * 2 + hw) ^ (krow & 7);
            bf16x8_t kf = *reinterpret_cast<const bf16x8_t*>(
                Kc + krow * 128 + phys * 16);
            sa[0] = __builtin_amdgcn_mfma_f32_32x32x16_bf16(kf, qfr[0][ks], sa[0], 0, 0, 0);
            sa[1] = __builtin_amdgcn_mfma_f32_32x32x16_bf16(kf, qfr[1][ks], sa[1], 0, 0, 0);
        }

        // ---- fixed-m softmax: p = 2^(s*c - 10); no max, no mask ops ----
        unsigned pku[2][8];
#pragma unroll
        for (int qi = 0; qi < 2; qi++) {
            float pv[16];
            float rs = 0.f;
#pragma unroll
            for (int r = 0; r < 16; r++) {
                pv[r] = exp2f(fmaf(sa[qi][r], SCALE_L2E, -FIXM));
                rs += pv[r];
            }
            l_run[qi] += rs;
#pragma unroll
            for (int s4 = 0; s4 < 4; s4++) {
                pku[qi][s4 * 2 + 0] = pack_bf16(pv[s4 * 4 + 0], pv[s4 * 4 + 1]);
                pku[qi][s4 * 2 + 1] = pack_bf16(pv[s4 * 4 + 2], pv[s4 * 4 + 3]);
            }
        }

        // ---- PV: O^T[d][q] += V^T · P  (wave's 32-kv strip = 2 k-chunks) ----
#pragma unroll
        for (int ks2 = 0; ks2 < 2; ks2++) {
            union { uint4 u; bf16x8_t f; } bw[2];
#pragma unroll
            for (int qi = 0; qi < 2; qi++) {
                int s_lo = ks2 * 2, s_own = ks2 * 2 + hw;
                unsigned send0 = hw ? pku[qi][s_lo * 2 + 0] : pku[qi][(s_lo + 1) * 2 + 0];
                unsigned send1 = hw ? pku[qi][s_lo * 2 + 1] : pku[qi][(s_lo + 1) * 2 + 1];
                unsigned recv0 = __shfl_xor((int)send0, 32, 64);
                unsigned recv1 = __shfl_xor((int)send1, 32, 64);
                bw[qi].u.x = hw ? recv0 : pku[qi][s_own * 2 + 0];
                bw[qi].u.y = hw ? recv1 : pku[qi][s_own * 2 + 1];
                bw[qi].u.z = hw ? pku[qi][s_own * 2 + 0] : recv0;
                bw[qi].u.w = hw ? pku[qi][s_own * 2 + 1] : recv1;
            }
#pragma unroll
            for (int ds = 0; ds < 2; ds++) {
                int vrow = ds * 32 + l31;
                int phys = (w * 4 + ks2 * 2 + hw) ^ (vrow & 15);
                bf16x8_t va = *reinterpret_cast<const bf16x8_t*>(
                    Vc + vrow * 256 + phys * 16);
                oacc[ds][0] = __builtin_amdgcn_mfma_f32_32x32x16_bf16(va, bw[0].f, oacc[ds][0], 0, 0, 0);
                oacc[ds][1] = __builtin_amdgcn_mfma_f32_32x32x16_bf16(va, bw[1].f, oacc[ds][1], 0, 0, 0);
            }
        }
    }

    // ---- in-block merge (pure sums; 32KB two-region buffer) ----
    l_run[0] += __shfl_xor(l_run[0], 32, 64);
    l_run[1] += __shfl_xor(l_run[1], 32, 64);
    if (hw == 0) { lsm[w][l31] = l_run[0]; lsm[w][32 + l31] = l_run[1]; }

    __syncthreads();   // all MFMA reads of staging done; OL may alias now
    if (w < 2) {
#pragma unroll
        for (int ds = 0; ds < 2; ds++)
#pragma unroll
            for (int qi = 0; qi < 2; qi++)
#pragma unroll
                for (int r = 0; r < 16; r++) {
                    int d = (r & 3) + 8 * (r >> 2) + 4 * hw + ds * 32;
                    int qq = qi * 32 + l31;
                    sm.OL[w * 4096 + d * 64 + ((qq + d) & 63)] = oacc[ds][qi][r];
                }
    }
    __syncthreads();
    if (w >= 2) {
#pragma unroll
        for (int ds = 0; ds < 2; ds++)
#pragma unroll
            for (int qi = 0; qi < 2; qi++)
#pragma unroll
                for (int r = 0; r < 16; r++) {
                    int d = (r & 3) + 8 * (r >> 2) + 4 * hw + ds * 32;
                    int qq = qi * 32 + l31;
                    int a = (w - 2) * 4096 + d * 64 + ((qq + d) & 63);
                    sm.OL[a] += oacc[ds][qi][r];
                }
    }
    __syncthreads();

    long obase = (((long)half * 32 + bh) * 1024 + q0) * HD;
#pragma unroll
    for (int qi2 = 0; qi2 < 16; qi2++) {
        int qq = w * 16 + qi2;
        float lt = lsm[0][qq] + lsm[1][qq] + lsm[2][qq] + lsm[3][qq];
        int col = (qq + lane) & 63;
        float ov = sm.OL[lane * 64 + col] + sm.OL[4096 + lane * 64 + col];
        Osc[obase + (long)qq * HD + lane] = ov;
        if (lane == 0) Lsc[((long)half * 32 + bh) * 1024 + q0 + qq] = lt;
    }
}

// ---------------- merge the two KV halves + normalize ----------------------
__global__ __launch_bounds__(256) void attn_merge(
    const float* __restrict__ Osc, const float* __restrict__ Lsc,
    const float* __restrict__ Sub, unsigned short* __restrict__ AO)
{
    int r = blockIdx.x * 4 + (threadIdx.x >> 6);   // bh*1024+q, 0..32767
    int d = threadIdx.x & 63;
    int bh = r >> 10, q = r & 1023;
    int b = bh >> 4, h = bh & 15;
    float o = Osc[(long)r * HD + d] + Osc[(long)(32768 + r) * HD + d];
    float l = Lsc[r] + Lsc[32768 + r] - Sub[b];
    AO[((long)(b * 1024 + q)) * E_DIM + h * HD + d] = f32_bf16(o / l);
}

// ---------------- LayerNorm over E=1024 ------------------------------------
__global__ __launch_bounds__(256) void ln_kernel(
    const float* __restrict__ x, const float* __restrict__ g,
    const float* __restrict__ be, float* __restrict__ out)
{
    __shared__ float red[8];
    int row = blockIdx.x, tid = threadIdx.x;
    float4 v = reinterpret_cast<const float4*>(x)[row * 256 + tid];
    float s  = v.x + v.y + v.z + v.w;
    float sq = v.x * v.x + v.y * v.y + v.z * v.z + v.w * v.w;
#pragma unroll
    for (int off = 32; off >= 1; off >>= 1) {
        s  += __shfl_xor(s,  off, 64);
        sq += __shfl_xor(sq, off, 64);
    }
    if ((tid & 63) == 0) { red[tid >> 6] = s; red[4 + (tid >> 6)] = sq; }
    __syncthreads();
    s  = red[0] + red[1] + red[2] + red[3];
    sq = red[4] + red[5] + red[6] + red[7];
    float mu  = s * (1.f / 1024.f);
    float var = sq * (1.f / 1024.f) - mu * mu;
    float rs  = rsqrtf(var + 1e-5f);
    int c = tid * 4;
    float4 o;
    o.x = (v.x - mu) * rs * g[c]     + be[c];
    o.y = (v.y - mu) * rs * g[c + 1] + be[c + 1];
    o.z = (v.z - mu) * rs * g[c + 2] + be[c + 2];
    o.w = (v.w - mu) * rs * g[c + 3] + be[c + 3];
    reinterpret_cast<float4*>(out)[row * 256 + tid] = o;
}

// ---------------------------------------------------------------------------
extern "C" void kernel_launch(void* const* d_in, const int* in_sizes, int n_in,
                              void* d_out, int out_size, void* d_ws, size_t ws_size,
                              hipStream_t stream) {
    const float* query     = (const float*)d_in[0];
    const float* key_value = (const float*)d_in[1];
    const int*   kv_mask   = (const int*)d_in[2];
    const float* Wq = (const float*)d_in[3];
    const float* bq = (const float*)d_in[4];
    const float* Wk = (const float*)d_in[5];
    const float* bk = (const float*)d_in[6];
    const float* Wv = (const float*)d_in[7];
    const float* bv = (const float*)d_in[8];
    const float* Wo = (const float*)d_in[9];
    const float* bo = (const float*)d_in[10];
    const float* ln_g = (const float*)d_in[11];
    const float* ln_b = (const float*)d_in[12];
    float* out = (float*)d_out;

    char* ws = (char*)d_ws;
    unsigned short* Xq  = (unsigned short*)(ws);                     // 4 MiB
    unsigned short* Xkv = (unsigned short*)(ws + (4ll  << 20));      // 16 MiB
    unsigned short* Wqb = (unsigned short*)(ws + (20ll << 20));      // 2 MiB
    unsigned short* Wkb = (unsigned short*)(ws + (22ll << 20));
    unsigned short* Wvb = (unsigned short*)(ws + (24ll << 20));
    unsigned short* Wob = (unsigned short*)(ws + (26ll << 20));
    unsigned short* Qh  = (unsigned short*)(ws + (28ll << 20));      // 4 MiB
    unsigned short* Kh  = (unsigned short*)(ws + (32ll << 20));      // 16 MiB
    unsigned short* VTh = (unsigned short*)(ws + (48ll << 20));      // 16 MiB
    unsigned short* AO  = (unsigned short*)(ws + (64ll << 20));      // 4 MiB
    float*          Xr  = (float*)(ws + (68ll << 20));               // 8 MiB
    float*          Osc = (float*)(ws + (76ll << 20));               // 16 MiB
    float*          Lsc = (float*)(ws + (92ll << 20));               // 256 KiB
    float*          Sub = (float*)(ws + (92ll << 20) + (256ll << 10)); // 8 B

    cast_all<<<14336, 256, 0, stream>>>(query, key_value, Wq, Wk, Wv, Wo,
                                        Xq, Xkv, Wqb, Wkb, Wvb, Wob);
    count_mask<<<2, 256, 0, stream>>>(kv_mask, Sub);

    gemm_qkv<<<dim3(8, 16), 256, 0, stream>>>(Xq,  Wqb, bq, Qh,  10, 0, kv_mask);
    gemm_qkv<<<dim3(8, 64), 256, 0, stream>>>(Xkv, Wkb, bk, Kh,  12, 1, kv_mask);
    gemm_qkv<<<dim3(8, 64), 256, 0, stream>>>(Xkv, Wvb, bv, VTh, 12, 2, kv_mask);

    attn_kernel<<<1024, 256, 0, stream>>>(Qh, Kh, VTh, Osc, Lsc);
    attn_merge<<<8192, 256, 0, stream>>>(Osc, Lsc, Sub, AO);

    gemm_oproj<<<dim3(8, 16), 256, 0, stream>>>(AO, Wob, bo, query, Xr);

    ln_kernel<<<2048, 256, 0, stream>>>(Xr, ln_g, ln_b, out);
}

// Round 6
// 330.997 us; speedup vs baseline: 2.1008x; 2.1008x over previous
//
#include <hip/hip_runtime.h>
#include <cstdint>

// ---------------------------------------------------------------------------
// CrossAttentionBlock: q/k/v proj (bf16 MFMA; K/V rows zeroed where masked) ->
// flash attention (32x32 MFMA, fixed-m softmax, wave+block KV split, pure-sum
// merges) -> merge -> o proj (+residual) -> LayerNorm.
// B=2, SQ=1024, SKV=4096, E=1024, H=16, D=64.
// Fixed-m softmax: p = 2^(s*log2e/8 - 10). Masked kv have K=V=0 => s==0
// exactly => p = 2^-10 exactly; contributes 0 to O and n_masked*2^-10 to l,
// subtracted at merge.
// NOTE: attn launch_bounds MUST be (256,2) — (256,4) caps unified VGPRs at
// 128 and spills the 64-AGPR accumulator state to scratch (R5: 1.45 GB of
// scratch writes, 468 us).
// ---------------------------------------------------------------------------

typedef __bf16 bf16x8_t  __attribute__((ext_vector_type(8)));
typedef float  f32x4_t   __attribute__((ext_vector_type(4)));
typedef float  f32x16_t  __attribute__((ext_vector_type(16)));

#define E_DIM 1024
#define NH    16
#define HD    64
#define SCALE_L2E 0.1803368804f   // (1/8) * log2(e)
#define FIXM  10.0f

__device__ __forceinline__ unsigned short f32_bf16(float f) {
    union { float f; unsigned int u; } v; v.f = f;
    unsigned int u = v.u;
    unsigned int r = (u + 0x7fffu + ((u >> 16) & 1u)) >> 16;  // RNE
    return (unsigned short)r;
}

__device__ __forceinline__ unsigned pack_bf16(float a, float b) {
    __bf16 x = (__bf16)a, y = (__bf16)b;
    unsigned short ux = __builtin_bit_cast(unsigned short, x);
    unsigned short uy = __builtin_bit_cast(unsigned short, y);
    return (unsigned)ux | ((unsigned)uy << 16);
}

// async global->LDS, 16B per lane; lds base must be wave-uniform
__device__ __forceinline__ void gld16(const unsigned short* g, unsigned short* l) {
    __builtin_amdgcn_global_load_lds(
        (const __attribute__((address_space(1))) unsigned int*)g,
        (__attribute__((address_space(3))) unsigned int*)l, 16, 0, 0);
}

// ---------------- fused fp32 -> bf16 casts (all 6 tensors) -----------------
__global__ void cast_all(const float* __restrict__ q, const float* __restrict__ kv,
                         const float* __restrict__ wq, const float* __restrict__ wk,
                         const float* __restrict__ wv, const float* __restrict__ wo,
                         unsigned short* __restrict__ Xq, unsigned short* __restrict__ Xkv,
                         unsigned short* __restrict__ Wqb, unsigned short* __restrict__ Wkb,
                         unsigned short* __restrict__ Wvb, unsigned short* __restrict__ Wob) {
    long i = (long)blockIdx.x * 256 + threadIdx.x;   // float4 index
    const float* src; unsigned short* dst; long off;
    if (i < 2621440) {
        if (i < 524288) { src = q;  dst = Xq;  off = i; }
        else            { src = kv; dst = Xkv; off = i - 524288; }
    } else {
        long j = i - 2621440;
        int w = (int)(j >> 18); off = j & 262143;
        src = (w == 0) ? wq : (w == 1) ? wk : (w == 2) ? wv : wo;
        dst = (w == 0) ? Wqb : (w == 1) ? Wkb : (w == 2) ? Wvb : Wob;
    }
    float4 v = reinterpret_cast<const float4*>(src)[off];
    ushort4 o;
    o.x = f32_bf16(v.x); o.y = f32_bf16(v.y);
    o.z = f32_bf16(v.z); o.w = f32_bf16(v.w);
    reinterpret_cast<ushort4*>(dst)[off] = o;
}

// ---------------- count masked kv per batch -> n_masked * 2^-10 ------------
__global__ void count_mask(const int* __restrict__ m, float* __restrict__ Sub) {
    __shared__ int red[4];
    int b = blockIdx.x, t = threadIdx.x;
    int s = 0;
#pragma unroll
    for (int k = 0; k < 16; k++) s += (m[b * 4096 + k * 256 + t] != 0);
#pragma unroll
    for (int off = 32; off >= 1; off >>= 1) s += __shfl_xor(s, off, 64);
    if ((t & 63) == 0) red[t >> 6] = s;
    __syncthreads();
    if (t == 0)
        Sub[b] = (float)(4096 - (red[0] + red[1] + red[2] + red[3])) * 0.0009765625f;
}

// ---------------- GEMM: C = A @ W^T + bias (m97-style staging) -------------
// mode 0: [B,H,S,D] (Q, no mask).  mode 1: [B,H,S,D], masked rows zeroed (K).
// mode 2: [B,H,D,S] (V^T), masked cols zeroed.
#define BM 128
#define BN 128
#define BK 64

__global__ __launch_bounds__(256) void gemm_qkv(
    const unsigned short* __restrict__ A,
    const unsigned short* __restrict__ W,
    const float* __restrict__ bias,
    unsigned short* __restrict__ out,
    int lgS, int mode, const int* __restrict__ kvm)
{
    __shared__ __align__(16) unsigned short As[BM * BK];
    __shared__ __align__(16) unsigned short Bs[BN * BK];
    int tid  = threadIdx.x;
    int m0   = blockIdx.y * BM;
    int n0   = blockIdx.x * BN;
    int lane = tid & 63;
    int wvu  = __builtin_amdgcn_readfirstlane(tid >> 6);
    int l15  = lane & 15, quad = lane >> 4, x7 = l15 & 7;
    int wm   = ((tid >> 6) >> 1) * 64, wn = ((tid >> 6) & 1) * 64;

    f32x4_t acc[4][4];
#pragma unroll
    for (int i = 0; i < 4; i++)
#pragma unroll
        for (int j = 0; j < 4; j++) acc[i][j] = (f32x4_t)(0.f);

    for (int k0 = 0; k0 < 1024; k0 += BK) {
        __syncthreads();
#pragma unroll
        for (int i = 0; i < 4; i++) {
            int s = (i * 4 + wvu) * 64 + lane;
            int row = s >> 3, pcol = ((s & 7) ^ (row & 7)) << 3;
            gld16(&A[(long)(m0 + row) * 1024 + k0 + pcol], &As[(i * 4 + wvu) * 512]);
            gld16(&W[(long)(n0 + row) * 1024 + k0 + pcol], &Bs[(i * 4 + wvu) * 512]);
        }
        __syncthreads();
        const char* Ab = (const char*)As;
        const char* Bb = (const char*)Bs;
#pragma unroll
        for (int ks = 0; ks < 2; ks++) {
            int pos = (((ks << 2) + quad) ^ x7) << 4;
            bf16x8_t af[4], bf[4];
#pragma unroll
            for (int mi = 0; mi < 4; mi++)
                af[mi] = *reinterpret_cast<const bf16x8_t*>(
                    Ab + (wm + mi * 16 + l15) * 128 + pos);
#pragma unroll
            for (int ni = 0; ni < 4; ni++)
                bf[ni] = *reinterpret_cast<const bf16x8_t*>(
                    Bb + (wn + ni * 16 + l15) * 128 + pos);
#pragma unroll
            for (int mi = 0; mi < 4; mi++)
#pragma unroll
                for (int ni = 0; ni < 4; ni++)
                    acc[mi][ni] = __builtin_amdgcn_mfma_f32_16x16x32_bf16(
                        af[mi], bf[ni], acc[mi][ni], 0, 0, 0);
        }
    }
    int Smask = (1 << lgS) - 1;
    if (mode == 0) {
#pragma unroll
        for (int mi = 0; mi < 4; mi++)
#pragma unroll
            for (int ni = 0; ni < 4; ni++) {
                int n = n0 + wn + ni * 16 + l15;
                float bv = bias[n];
                int h = n >> 6, d = n & 63;
#pragma unroll
                for (int r = 0; r < 4; r++) {
                    int mg = m0 + wm + mi * 16 + quad * 4 + r;
                    int b = mg >> lgS, s = mg & Smask;
                    out[(((b * NH + h) << lgS) + s) * HD + d] =
                        f32_bf16(acc[mi][ni][r] + bv);
                }
            }
    } else if (mode == 1) {
#pragma unroll
        for (int mi = 0; mi < 4; mi++)
#pragma unroll
            for (int ni = 0; ni < 4; ni++) {
                int n = n0 + wn + ni * 16 + l15;
                float bv = bias[n];
                int h = n >> 6, d = n & 63;
#pragma unroll
                for (int r = 0; r < 4; r++) {
                    int mg = m0 + wm + mi * 16 + quad * 4 + r;
                    int b = mg >> lgS, s = mg & Smask;
                    unsigned short val = kvm[(b << lgS) + s]
                        ? f32_bf16(acc[mi][ni][r] + bv) : (unsigned short)0;
                    out[(((b * NH + h) << lgS) + s) * HD + d] = val;
                }
            }
    } else {
#pragma unroll
        for (int mi = 0; mi < 4; mi++)
#pragma unroll
            for (int ni = 0; ni < 4; ni++) {
                int n = n0 + wn + ni * 16 + l15;
                float bv = bias[n];
                int h = n >> 6, d = n & 63;
                int mg0 = m0 + wm + mi * 16 + quad * 4;
                int b = mg0 >> lgS, s = mg0 & Smask;
                int4 mk = *reinterpret_cast<const int4*>(&kvm[(b << lgS) + s]);
                ushort4 w;
                w.x = mk.x ? f32_bf16(acc[mi][ni][0] + bv) : (unsigned short)0;
                w.y = mk.y ? f32_bf16(acc[mi][ni][1] + bv) : (unsigned short)0;
                w.z = mk.z ? f32_bf16(acc[mi][ni][2] + bv) : (unsigned short)0;
                w.w = mk.w ? f32_bf16(acc[mi][ni][3] + bv) : (unsigned short)0;
                *reinterpret_cast<ushort4*>(
                    &out[(((b * NH + h) * HD + d) << lgS) + s]) = w;
            }
    }
}

// ---------------- O-proj GEMM + bias + residual -> fp32 --------------------
__global__ __launch_bounds__(256) void gemm_oproj(
    const unsigned short* __restrict__ A,
    const unsigned short* __restrict__ W,
    const float* __restrict__ bias,
    const float* __restrict__ resid,
    float* __restrict__ xout)
{
    __shared__ __align__(16) unsigned short As[BM * BK];
    __shared__ __align__(16) unsigned short Bs[BN * BK];
    int tid  = threadIdx.x;
    int m0   = blockIdx.y * BM;
    int n0   = blockIdx.x * BN;
    int lane = tid & 63;
    int wvu  = __builtin_amdgcn_readfirstlane(tid >> 6);
    int l15  = lane & 15, quad = lane >> 4, x7 = l15 & 7;
    int wm   = ((tid >> 6) >> 1) * 64, wn = ((tid >> 6) & 1) * 64;

    f32x4_t acc[4][4];
#pragma unroll
    for (int i = 0; i < 4; i++)
#pragma unroll
        for (int j = 0; j < 4; j++) acc[i][j] = (f32x4_t)(0.f);

    for (int k0 = 0; k0 < 1024; k0 += BK) {
        __syncthreads();
#pragma unroll
        for (int i = 0; i < 4; i++) {
            int s = (i * 4 + wvu) * 64 + lane;
            int row = s >> 3, pcol = ((s & 7) ^ (row & 7)) << 3;
            gld16(&A[(long)(m0 + row) * 1024 + k0 + pcol], &As[(i * 4 + wvu) * 512]);
            gld16(&W[(long)(n0 + row) * 1024 + k0 + pcol], &Bs[(i * 4 + wvu) * 512]);
        }
        __syncthreads();
        const char* Ab = (const char*)As;
        const char* Bb = (const char*)Bs;
#pragma unroll
        for (int ks = 0; ks < 2; ks++) {
            int pos = (((ks << 2) + quad) ^ x7) << 4;
            bf16x8_t af[4], bf[4];
#pragma unroll
            for (int mi = 0; mi < 4; mi++)
                af[mi] = *reinterpret_cast<const bf16x8_t*>(
                    Ab + (wm + mi * 16 + l15) * 128 + pos);
#pragma unroll
            for (int ni = 0; ni < 4; ni++)
                bf[ni] = *reinterpret_cast<const bf16x8_t*>(
                    Bb + (wn + ni * 16 + l15) * 128 + pos);
#pragma unroll
            for (int mi = 0; mi < 4; mi++)
#pragma unroll
                for (int ni = 0; ni < 4; ni++)
                    acc[mi][ni] = __builtin_amdgcn_mfma_f32_16x16x32_bf16(
                        af[mi], bf[ni], acc[mi][ni], 0, 0, 0);
        }
    }
#pragma unroll
    for (int mi = 0; mi < 4; mi++)
#pragma unroll
        for (int ni = 0; ni < 4; ni++) {
            int n = n0 + wn + ni * 16 + l15;
            float bv = bias[n];
#pragma unroll
            for (int r = 0; r < 4; r++) {
                int mg = m0 + wm + mi * 16 + quad * 4 + r;
                xout[mg * 1024 + n] = acc[mi][ni][r] + bv + resid[mg * 1024 + n];
            }
        }
}

// ---------------- flash attention (32x32 MFMA, fixed-m, kv-split) ----------
// grid 1024 blocks of 256.  Block = 64 q of one (b,h) x one kv half (2048).
// Waves own 32-kv strips of each 128 tile.  No online max: p=2^(s*c-10).
__global__ __launch_bounds__(256, 2) void attn_kernel(
    const unsigned short* __restrict__ Q,   // [B,NH,1024,64]
    const unsigned short* __restrict__ K,   // [B,NH,4096,64]  masked rows = 0
    const unsigned short* __restrict__ VT,  // [B,NH,64,4096]  masked cols = 0
    float* __restrict__ Osc,                // [2][32][1024][64] fp32 partial O
    float* __restrict__ Lsc)                // [2][32][1024] partial l
{
    __shared__ __align__(16) union {
        struct { unsigned short Ks[128 * 64]; unsigned short Vt[64 * 128]; } st;
        float OL[2 * 4096];                 // two 16KB merge regions
    } sm;
    __shared__ float lsm[4][64];

    int tid  = threadIdx.x;
    int lane = tid & 63;
    int w    = tid >> 6;
    int wvu  = __builtin_amdgcn_readfirstlane(w);
    int l31  = lane & 31, hw = lane >> 5;

    // XCD-grouped: 4 (b,h) per XCD; q-tiles and halves of one bh share L2
    int bid  = blockIdx.x;
    int xcd  = bid & 7, gidx = bid >> 3;
    int bh   = xcd * 4 + (gidx & 3);
    int rest = gidx >> 2;                    // 0..31
    int q0   = (rest & 15) * 64;
    int half = rest >> 4;

    const unsigned short* Kb = K + ((long)bh * 4096 + half * 2048) * HD;
    const unsigned short* Vb = VT + (long)bh * HD * 4096 + half * 2048;
    const unsigned short* Qb = Q + ((long)bh * 1024 + q0) * HD;

    // Q fragments (B-operand): B[n=q=l31][k=hw*8+j], 2 q-subtiles x 4 k-chunks
    bf16x8_t qfr[2][4];
#pragma unroll
    for (int qi = 0; qi < 2; qi++)
#pragma unroll
        for (int ks = 0; ks < 4; ks++)
            qfr[qi][ks] = *reinterpret_cast<const bf16x8_t*>(
                Qb + (qi * 32 + l31) * HD + ks * 16 + hw * 8);

    f32x16_t oacc[2][2];
#pragma unroll
    for (int i = 0; i < 2; i++)
#pragma unroll
        for (int j = 0; j < 2; j++) oacc[i][j] = (f32x16_t)(0.f);
    float l_run[2] = { 0.f, 0.f };

    const char* Kc = (const char*)sm.st.Ks;
    const char* Vc = (const char*)sm.st.Vt;

    for (int kt = 0; kt < 16; kt++) {
        int kv0 = kt * 128;
        __syncthreads();
#pragma unroll
        for (int i = 0; i < 4; i++) {
            int s = (i * 4 + wvu) * 64 + lane;
            int row = s >> 3, pc = ((s & 7) ^ (row & 7)) << 3;
            gld16(&Kb[(long)(kv0 + row) * HD + pc], &sm.st.Ks[(i * 4 + wvu) * 512]);
            int rv = s >> 4, pv2 = ((s & 15) ^ (rv & 15)) << 3;
            gld16(&Vb[(long)rv * 4096 + kv0 + pv2], &sm.st.Vt[(i * 4 + wvu) * 512]);
        }
        __syncthreads();

        // ---- S^T: C[kv 32][q 32] per q-subtile; kv rows = w*32.. ----
        f32x16_t sa[2];
        sa[0] = (f32x16_t)(0.f); sa[1] = (f32x16_t)(0.f);
        int krow = w * 32 + l31;
#pragma unroll
        for (int ks = 0; ks < 4; ks++) {
            int phys = (ks * 2 + hw) ^ (krow & 7);
            bf16x8_t kf = *reinterpret_cast<const bf16x8_t*>(
                Kc + krow * 128 + phys * 16);
            sa[0] = __builtin_amdgcn_mfma_f32_32x32x16_bf16(kf, qfr[0][ks], sa[0], 0, 0, 0);
            sa[1] = __builtin_amdgcn_mfma_f32_32x32x16_bf16(kf, qfr[1][ks], sa[1], 0, 0, 0);
        }

        // ---- fixed-m softmax: p = 2^(s*c - 10); no max, no mask ops ----
        unsigned pku[2][8];
#pragma unroll
        for (int qi = 0; qi < 2; qi++) {
            float pv[16];
            float rs = 0.f;
#pragma unroll
            for (int r = 0; r < 16; r++) {
                pv[r] = exp2f(fmaf(sa[qi][r], SCALE_L2E, -FIXM));
                rs += pv[r];
            }
            l_run[qi] += rs;
#pragma unroll
            for (int s4 = 0; s4 < 4; s4++) {
                pku[qi][s4 * 2 + 0] = pack_bf16(pv[s4 * 4 + 0], pv[s4 * 4 + 1]);
                pku[qi][s4 * 2 + 1] = pack_bf16(pv[s4 * 4 + 2], pv[s4 * 4 + 3]);
            }
        }

        // ---- PV: O^T[d][q] += V^T · P  (wave's 32-kv strip = 2 k-chunks) ----
#pragma unroll
        for (int ks2 = 0; ks2 < 2; ks2++) {
            union { uint4 u; bf16x8_t f; } bw[2];
#pragma unroll
            for (int qi = 0; qi < 2; qi++) {
                int s_lo = ks2 * 2, s_own = ks2 * 2 + hw;
                unsigned send0 = hw ? pku[qi][s_lo * 2 + 0] : pku[qi][(s_lo + 1) * 2 + 0];
                unsigned send1 = hw ? pku[qi][s_lo * 2 + 1] : pku[qi][(s_lo + 1) * 2 + 1];
                unsigned recv0 = __shfl_xor((int)send0, 32, 64);
                unsigned recv1 = __shfl_xor((int)send1, 32, 64);
                bw[qi].u.x = hw ? recv0 : pku[qi][s_own * 2 + 0];
                bw[qi].u.y = hw ? recv1 : pku[qi][s_own * 2 + 1];
                bw[qi].u.z = hw ? pku[qi][s_own * 2 + 0] : recv0;
                bw[qi].u.w = hw ? pku[qi][s_own * 2 + 1] : recv1;
            }
#pragma unroll
            for (int ds = 0; ds < 2; ds++) {
                int vrow = ds * 32 + l31;
                int phys = (w * 4 + ks2 * 2 + hw) ^ (vrow & 15);
                bf16x8_t va = *reinterpret_cast<const bf16x8_t*>(
                    Vc + vrow * 256 + phys * 16);
                oacc[ds][0] = __builtin_amdgcn_mfma_f32_32x32x16_bf16(va, bw[0].f, oacc[ds][0], 0, 0, 0);
                oacc[ds][1] = __builtin_amdgcn_mfma_f32_32x32x16_bf16(va, bw[1].f, oacc[ds][1], 0, 0, 0);
            }
        }
    }

    // ---- in-block merge (pure sums; 32KB two-region buffer) ----
    l_run[0] += __shfl_xor(l_run[0], 32, 64);
    l_run[1] += __shfl_xor(l_run[1], 32, 64);
    if (hw == 0) { lsm[w][l31] = l_run[0]; lsm[w][32 + l31] = l_run[1]; }

    __syncthreads();   // all MFMA reads of staging done; OL may alias now
    if (w < 2) {
#pragma unroll
        for (int ds = 0; ds < 2; ds++)
#pragma unroll
            for (int qi = 0; qi < 2; qi++)
#pragma unroll
                for (int r = 0; r < 16; r++) {
                    int d = (r & 3) + 8 * (r >> 2) + 4 * hw + ds * 32;
                    int qq = qi * 32 + l31;
                    sm.OL[w * 4096 + d * 64 + ((qq + d) & 63)] = oacc[ds][qi][r];
                }
    }
    __syncthreads();
    if (w >= 2) {
#pragma unroll
        for (int ds = 0; ds < 2; ds++)
#pragma unroll
            for (int qi = 0; qi < 2; qi++)
#pragma unroll
                for (int r = 0; r < 16; r++) {
                    int d = (r & 3) + 8 * (r >> 2) + 4 * hw + ds * 32;
                    int qq = qi * 32 + l31;
                    int a = (w - 2) * 4096 + d * 64 + ((qq + d) & 63);
                    sm.OL[a] += oacc[ds][qi][r];
                }
    }
    __syncthreads();

    long obase = (((long)half * 32 + bh) * 1024 + q0) * HD;
#pragma unroll
    for (int qi2 = 0; qi2 < 16; qi2++) {
        int qq = w * 16 + qi2;
        float lt = lsm[0][qq] + lsm[1][qq] + lsm[2][qq] + lsm[3][qq];
        int col = (qq + lane) & 63;
        float ov = sm.OL[lane * 64 + col] + sm.OL[4096 + lane * 64 + col];
        Osc[obase + (long)qq * HD + lane] = ov;
        if (lane == 0) Lsc[((long)half * 32 + bh) * 1024 + q0 + qq] = lt;
    }
}

// ---------------- merge the two KV halves + normalize ----------------------
__global__ __launch_bounds__(256) void attn_merge(
    const float* __restrict__ Osc, const float* __restrict__ Lsc,
    const float* __restrict__ Sub, unsigned short* __restrict__ AO)
{
    int r = blockIdx.x * 4 + (threadIdx.x >> 6);   // bh*1024+q, 0..32767
    int d = threadIdx.x & 63;
    int bh = r >> 10, q = r & 1023;
    int b = bh >> 4, h = bh & 15;
    float o = Osc[(long)r * HD + d] + Osc[(long)(32768 + r) * HD + d];
    float l = Lsc[r] + Lsc[32768 + r] - Sub[b];
    AO[((long)(b * 1024 + q)) * E_DIM + h * HD + d] = f32_bf16(o / l);
}

// ---------------- LayerNorm over E=1024 ------------------------------------
__global__ __launch_bounds__(256) void ln_kernel(
    const float* __restrict__ x, const float* __restrict__ g,
    const float* __restrict__ be, float* __restrict__ out)
{
    __shared__ float red[8];
    int row = blockIdx.x, tid = threadIdx.x;
    float4 v = reinterpret_cast<const float4*>(x)[row * 256 + tid];
    float s  = v.x + v.y + v.z + v.w;
    float sq = v.x * v.x + v.y * v.y + v.z * v.z + v.w * v.w;
#pragma unroll
    for (int off = 32; off >= 1; off >>= 1) {
        s  += __shfl_xor(s,  off, 64);
        sq += __shfl_xor(sq, off, 64);
    }
    if ((tid & 63) == 0) { red[tid >> 6] = s; red[4 + (tid >> 6)] = sq; }
    __syncthreads();
    s  = red[0] + red[1] + red[2] + red[3];
    sq = red[4] + red[5] + red[6] + red[7];
    float mu  = s * (1.f / 1024.f);
    float var = sq * (1.f / 1024.f) - mu * mu;
    float rs  = rsqrtf(var + 1e-5f);
    int c = tid * 4;
    float4 o;
    o.x = (v.x - mu) * rs * g[c]     + be[c];
    o.y = (v.y - mu) * rs * g[c + 1] + be[c + 1];
    o.z = (v.z - mu) * rs * g[c + 2] + be[c + 2];
    o.w = (v.w - mu) * rs * g[c + 3] + be[c + 3];
    reinterpret_cast<float4*>(out)[row * 256 + tid] = o;
}

// ---------------------------------------------------------------------------
extern "C" void kernel_launch(void* const* d_in, const int* in_sizes, int n_in,
                              void* d_out, int out_size, void* d_ws, size_t ws_size,
                              hipStream_t stream) {
    const float* query     = (const float*)d_in[0];
    const float* key_value = (const float*)d_in[1];
    const int*   kv_mask   = (const int*)d_in[2];
    const float* Wq = (const float*)d_in[3];
    const float* bq = (const float*)d_in[4];
    const float* Wk = (const float*)d_in[5];
    const float* bk = (const float*)d_in[6];
    const float* Wv = (const float*)d_in[7];
    const float* bv = (const float*)d_in[8];
    const float* Wo = (const float*)d_in[9];
    const float* bo = (const float*)d_in[10];
    const float* ln_g = (const float*)d_in[11];
    const float* ln_b = (const float*)d_in[12];
    float* out = (float*)d_out;

    char* ws = (char*)d_ws;
    unsigned short* Xq  = (unsigned short*)(ws);                     // 4 MiB
    unsigned short* Xkv = (unsigned short*)(ws + (4ll  << 20));      // 16 MiB
    unsigned short* Wqb = (unsigned short*)(ws + (20ll << 20));      // 2 MiB
    unsigned short* Wkb = (unsigned short*)(ws + (22ll << 20));
    unsigned short* Wvb = (unsigned short*)(ws + (24ll << 20));
    unsigned short* Wob = (unsigned short*)(ws + (26ll << 20));
    unsigned short* Qh  = (unsigned short*)(ws + (28ll << 20));      // 4 MiB
    unsigned short* Kh  = (unsigned short*)(ws + (32ll << 20));      // 16 MiB
    unsigned short* VTh = (unsigned short*)(ws + (48ll << 20));      // 16 MiB
    unsigned short* AO  = (unsigned short*)(ws + (64ll << 20));      // 4 MiB
    float*          Xr  = (float*)(ws + (68ll << 20));               // 8 MiB
    float*          Osc = (float*)(ws + (76ll << 20));               // 16 MiB
    float*          Lsc = (float*)(ws + (92ll << 20));               // 256 KiB
    float*          Sub = (float*)(ws + (92ll << 20) + (256ll << 10)); // 8 B

    cast_all<<<14336, 256, 0, stream>>>(query, key_value, Wq, Wk, Wv, Wo,
                                        Xq, Xkv, Wqb, Wkb, Wvb, Wob);
    count_mask<<<2, 256, 0, stream>>>(kv_mask, Sub);

    gemm_qkv<<<dim3(8, 16), 256, 0, stream>>>(Xq,  Wqb, bq, Qh,  10, 0, kv_mask);
    gemm_qkv<<<dim3(8, 64), 256, 0, stream>>>(Xkv, Wkb, bk, Kh,  12, 1, kv_mask);
    gemm_qkv<<<dim3(8, 64), 256, 0, stream>>>(Xkv, Wvb, bv, VTh, 12, 2, kv_mask);

    attn_kernel<<<1024, 256, 0, stream>>>(Qh, Kh, VTh, Osc, Lsc);
    attn_merge<<<8192, 256, 0, stream>>>(Osc, Lsc, Sub, AO);

    gemm_oproj<<<dim3(8, 16), 256, 0, stream>>>(AO, Wob, bo, query, Xr);

    ln_kernel<<<2048, 256, 0, stream>>>(Xr, ln_g, ln_b, out);
}